// Round 1
// baseline (723.714 us; speedup 1.0000x reference)
//
#include <hip/hip_runtime.h>
#include <climits>

#define IN_F 4096
#define OUT_F 4096
#define BATCH 4096

typedef __bf16 bf16x8 __attribute__((ext_vector_type(8)));
typedef float f32x4 __attribute__((ext_vector_type(4)));

__device__ __forceinline__ unsigned short f2bf_rne(float f) {
  unsigned int u = __float_as_uint(f);
  u += 0x7fffu + ((u >> 16) & 1u);
  return (unsigned short)(u >> 16);
}

// ---------------- init min/max slots ----------------
__global__ void k_init(int* mm) {
  mm[0] = INT_MAX; mm[1] = INT_MIN;   // weight qmin/qmax
  mm[2] = INT_MAX; mm[3] = INT_MIN;   // bias qmin/qmax
}

// ---------------- convert weights int32 -> bf16 (exact), fused min/max ----------------
__global__ void k_convq(const int* __restrict__ q, unsigned short* __restrict__ qb,
                        int* __restrict__ mm) {
  const int n4 = (OUT_F * IN_F) / 4;
  const int stride = gridDim.x * blockDim.x;
  int vmin = INT_MAX, vmax = INT_MIN;
  const int4* q4 = (const int4*)q;
  ushort4* qb4 = (ushort4*)qb;
  for (int i = blockIdx.x * blockDim.x + threadIdx.x; i < n4; i += stride) {
    int4 v = q4[i];
    vmin = min(vmin, min(min(v.x, v.y), min(v.z, v.w)));
    vmax = max(vmax, max(max(v.x, v.y), max(v.z, v.w)));
    ushort4 h;
    h.x = f2bf_rne((float)v.x);  // |q| <= 255 -> exact in bf16
    h.y = f2bf_rne((float)v.y);
    h.z = f2bf_rne((float)v.z);
    h.w = f2bf_rne((float)v.w);
    qb4[i] = h;
  }
  for (int off = 32; off > 0; off >>= 1) {
    vmin = min(vmin, __shfl_down(vmin, off));
    vmax = max(vmax, __shfl_down(vmax, off));
  }
  if ((threadIdx.x & 63) == 0) {
    atomicMin(&mm[0], vmin);
    atomicMax(&mm[1], vmax);
  }
}

// ---------------- weight min/max only (fallback path) ----------------
__global__ void k_wmm(const int* __restrict__ q, int* __restrict__ mm) {
  const int n4 = (OUT_F * IN_F) / 4;
  const int stride = gridDim.x * blockDim.x;
  int vmin = INT_MAX, vmax = INT_MIN;
  const int4* q4 = (const int4*)q;
  for (int i = blockIdx.x * blockDim.x + threadIdx.x; i < n4; i += stride) {
    int4 v = q4[i];
    vmin = min(vmin, min(min(v.x, v.y), min(v.z, v.w)));
    vmax = max(vmax, max(max(v.x, v.y), max(v.z, v.w)));
  }
  for (int off = 32; off > 0; off >>= 1) {
    vmin = min(vmin, __shfl_down(vmin, off));
    vmax = max(vmax, __shfl_down(vmax, off));
  }
  if ((threadIdx.x & 63) == 0) {
    atomicMin(&mm[0], vmin);
    atomicMax(&mm[1], vmax);
  }
}

// ---------------- convert x fp32 -> bf16, fused row sums ----------------
__global__ void k_convx(const float* __restrict__ x, unsigned short* __restrict__ xb,
                        float* __restrict__ rowsum) {
  const int row = blockIdx.x;
  const float4* xr = (const float4*)(x + (size_t)row * IN_F);
  ushort4* xbr = (ushort4*)(xb + (size_t)row * IN_F);
  float s = 0.f;
  for (int i = threadIdx.x; i < IN_F / 4; i += blockDim.x) {
    float4 v = xr[i];
    s += (v.x + v.y) + (v.z + v.w);
    ushort4 h;
    h.x = f2bf_rne(v.x); h.y = f2bf_rne(v.y);
    h.z = f2bf_rne(v.z); h.w = f2bf_rne(v.w);
    xbr[i] = h;
  }
  __shared__ float red[4];
  for (int off = 32; off > 0; off >>= 1) s += __shfl_down(s, off);
  if ((threadIdx.x & 63) == 0) red[threadIdx.x >> 6] = s;
  __syncthreads();
  if (threadIdx.x == 0) rowsum[row] = (red[0] + red[1]) + (red[2] + red[3]);
}

// ---------------- bias min/max ----------------
__global__ void k_biasmm(const int* __restrict__ bq, int* __restrict__ mm) {
  int vmin = INT_MAX, vmax = INT_MIN;
  for (int i = threadIdx.x; i < OUT_F; i += blockDim.x) {
    int v = bq[i];
    vmin = min(vmin, v);
    vmax = max(vmax, v);
  }
  for (int off = 32; off > 0; off >>= 1) {
    vmin = min(vmin, __shfl_down(vmin, off));
    vmax = max(vmax, __shfl_down(vmax, off));
  }
  if ((threadIdx.x & 63) == 0) {
    atomicMin(&mm[2], vmin);
    atomicMax(&mm[3], vmax);
  }
}

// ---------------- compute affine dequant scalars ----------------
__global__ void k_final(const int* __restrict__ mm,
                        const float* __restrict__ wmn, const float* __restrict__ wmx,
                        const float* __restrict__ bmn, const float* __restrict__ bmx,
                        float* __restrict__ scal) {
  float ws = (*wmx - *wmn) / (float)(mm[1] - mm[0]);
  scal[0] = ws;
  scal[1] = *wmn - ws * (float)mm[0];
  float bs = (*bmx - *bmn) / (float)(mm[3] - mm[2]);
  scal[2] = bs;
  scal[3] = *bmn - bs * (float)mm[2];
}

// ---------------- async global->LDS, 16B per lane, wave-uniform LDS base ----------------
__device__ __forceinline__ void load_lds16(const unsigned short* g, unsigned short* l) {
  __builtin_amdgcn_global_load_lds(
      (const __attribute__((address_space(1))) unsigned int*)g,
      (__attribute__((address_space(3))) unsigned int*)l, 16, 0, 0);
}

// ---------------- 128x128-tile bf16 MFMA GEMM: C = A @ B^T (both K-contiguous) ----------------
// epilogue: out = wscale*acc + wbeta*rowsum[m] + (bscale*bias_q[n] + bbeta)
__global__ __launch_bounds__(256) void k_gemm(
    const unsigned short* __restrict__ A,   // x   bf16 [BATCH][IN_F]
    const unsigned short* __restrict__ B,   // Q   bf16 [OUT_F][IN_F]
    const int* __restrict__ bq,
    const float* __restrict__ rowsum,
    const float* __restrict__ scal,
    float* __restrict__ C) {
  __shared__ unsigned short As[128 * 32];   // 8 KB, row-major [128][32], NO padding (global_load_lds)
  __shared__ unsigned short Bs[128 * 32];

  const int tid = threadIdx.x;
  const int wave = tid >> 6;
  const int lane = tid & 63;
  const int bm = blockIdx.x * 128;
  const int bn = blockIdx.y * 128;

  const int wm = (wave & 1) * 64;   // wave's 64x64 subtile
  const int wn = (wave >> 1) * 64;
  const int row16 = lane & 15;
  const int quad = lane >> 4;

  // staging: 8 chunks of 1KB per tile (64 lanes x 16B); wave handles chunks 2w, 2w+1
  const int c0 = wave * 2;
  const int r0 = c0 * 16 + (lane >> 2);
  const int r1 = r0 + 16;
  const int ccol = (lane & 3) * 8;
  const unsigned short* Ap0 = A + (size_t)(bm + r0) * IN_F + ccol;
  const unsigned short* Ap1 = A + (size_t)(bm + r1) * IN_F + ccol;
  const unsigned short* Bp0 = B + (size_t)(bn + r0) * IN_F + ccol;
  const unsigned short* Bp1 = B + (size_t)(bn + r1) * IN_F + ccol;
  unsigned short* As0 = &As[c0 * 512];
  unsigned short* As1 = &As[(c0 + 1) * 512];
  unsigned short* Bs0 = &Bs[c0 * 512];
  unsigned short* Bs1 = &Bs[(c0 + 1) * 512];

  f32x4 acc[4][4] = {};

  for (int k0 = 0; k0 < IN_F; k0 += 32) {
    load_lds16(Ap0 + k0, As0);
    load_lds16(Ap1 + k0, As1);
    load_lds16(Bp0 + k0, Bs0);
    load_lds16(Bp1 + k0, Bs1);
    __syncthreads();   // drains vmcnt -> LDS tiles ready

    bf16x8 af[4], bfr[4];
#pragma unroll
    for (int i = 0; i < 4; ++i)
      af[i] = *(const bf16x8*)&As[(wm + i * 16 + row16) * 32 + quad * 8];
#pragma unroll
    for (int i = 0; i < 4; ++i)
      bfr[i] = *(const bf16x8*)&Bs[(wn + i * 16 + row16) * 32 + quad * 8];
#pragma unroll
    for (int mi = 0; mi < 4; ++mi)
#pragma unroll
      for (int ni = 0; ni < 4; ++ni)
        acc[mi][ni] = __builtin_amdgcn_mfma_f32_16x16x32_bf16(af[mi], bfr[ni], acc[mi][ni], 0, 0, 0);

    __syncthreads();   // all reads done before next overwrite
  }

  const float wsc = scal[0], wbe = scal[1], bsc = scal[2], bbe = scal[3];
#pragma unroll
  for (int ni = 0; ni < 4; ++ni) {
    const int gn = bn + wn + ni * 16 + row16;          // C/D: col = lane&15
    const float bdq = bsc * (float)bq[gn] + bbe;
#pragma unroll
    for (int mi = 0; mi < 4; ++mi) {
      const int gm0 = bm + wm + mi * 16 + quad * 4;    // C/D: row = quad*4 + reg
#pragma unroll
      for (int r = 0; r < 4; ++r) {
        const int gm = gm0 + r;
        C[(size_t)gm * OUT_F + gn] = wsc * acc[mi][ni][r] + wbe * rowsum[gm] + bdq;
      }
    }
  }
}

// ---------------- fallback (workspace too small): dequant-on-the-fly naive GEMM ----------------
__global__ void k_naive(const float* __restrict__ x, const int* __restrict__ wq,
                        const int* __restrict__ bq, const float* __restrict__ scal,
                        float* __restrict__ out) {
  const int o = blockIdx.x * blockDim.x + threadIdx.x;
  const int b = blockIdx.y;
  const float* xr = x + (size_t)b * IN_F;
  const int* wr = wq + (size_t)o * IN_F;
  float s = 0.f, sx = 0.f;
  for (int k = 0; k < IN_F; ++k) {
    float xv = xr[k];
    s += xv * (float)wr[k];
    sx += xv;
  }
  out[(size_t)b * OUT_F + o] =
      scal[0] * s + scal[1] * sx + scal[2] * (float)bq[o] + scal[3];
}

extern "C" void kernel_launch(void* const* d_in, const int* in_sizes, int n_in,
                              void* d_out, int out_size, void* d_ws, size_t ws_size,
                              hipStream_t stream) {
  const float* x = (const float*)d_in[0];
  const int* wq = (const int*)d_in[1];
  const int* bq = (const int*)d_in[2];
  const float* wmn = (const float*)d_in[3];
  const float* wmx = (const float*)d_in[4];
  const float* bmn = (const float*)d_in[5];
  const float* bmx = (const float*)d_in[6];
  float* out = (float*)d_out;

  char* ws = (char*)d_ws;
  int* mm = (int*)ws;                              // 16 B
  float* scal = (float*)(ws + 16);                 // 16 B
  float* rowsum = (float*)(ws + 64);               // 16 KB
  unsigned short* xb = (unsigned short*)(ws + 64 + BATCH * sizeof(float));
  unsigned short* qb = xb + (size_t)BATCH * IN_F;
  const size_t needed = 64 + (size_t)BATCH * 4 +
                        (size_t)BATCH * IN_F * 2 + (size_t)OUT_F * IN_F * 2;

  k_init<<<1, 1, 0, stream>>>(mm);
  k_biasmm<<<1, 256, 0, stream>>>(bq, mm);

  if (ws_size >= needed) {
    k_convq<<<4096, 256, 0, stream>>>(wq, qb, mm);
    k_convx<<<BATCH, 256, 0, stream>>>(x, xb, rowsum);
    k_final<<<1, 1, 0, stream>>>(mm, wmn, wmx, bmn, bmx, scal);
    dim3 grid(BATCH / 128, OUT_F / 128);
    k_gemm<<<grid, 256, 0, stream>>>(xb, qb, bq, rowsum, scal, out);
  } else {
    k_wmm<<<2048, 256, 0, stream>>>(wq, mm);
    k_final<<<1, 1, 0, stream>>>(mm, wmn, wmx, bmn, bmx, scal);
    k_naive<<<dim3(OUT_F / 256, BATCH), 256, 0, stream>>>(x, wq, bq, scal, out);
  }
}

// Round 2
// 360.396 us; speedup vs baseline: 2.0081x; 2.0081x over previous
//
#include <hip/hip_runtime.h>
#include <climits>

#define IN_F 4096
#define OUT_F 4096
#define BATCH 4096
#define NPART 1024   // partial-reduction slots for weight min/max

typedef __bf16 bf16x8 __attribute__((ext_vector_type(8)));
typedef float f32x4 __attribute__((ext_vector_type(4)));

__device__ __forceinline__ unsigned short f2bf_rne(float f) {
  unsigned int u = __float_as_uint(f);
  u += 0x7fffu + ((u >> 16) & 1u);
  return (unsigned short)(u >> 16);
}

// ---------------- convert weights int32 -> bf16 (exact), per-block partial min/max ----------------
// NO global atomics: 16K same-address atomicMin/Max serialized at ~28cyc each = 383us in R1.
__global__ __launch_bounds__(256) void k_convq(const int* __restrict__ q,
                                               unsigned short* __restrict__ qb,
                                               int* __restrict__ pmin,
                                               int* __restrict__ pmax) {
  const int n4 = (OUT_F * IN_F) / 4;
  const int stride = gridDim.x * blockDim.x;
  int vmin = INT_MAX, vmax = INT_MIN;
  const int4* q4 = (const int4*)q;
  ushort4* qb4 = (ushort4*)qb;
  for (int i = blockIdx.x * blockDim.x + threadIdx.x; i < n4; i += stride) {
    int4 v = q4[i];
    vmin = min(vmin, min(min(v.x, v.y), min(v.z, v.w)));
    vmax = max(vmax, max(max(v.x, v.y), max(v.z, v.w)));
    ushort4 h;
    h.x = f2bf_rne((float)v.x);  // |q| <= 255 -> exact in bf16
    h.y = f2bf_rne((float)v.y);
    h.z = f2bf_rne((float)v.z);
    h.w = f2bf_rne((float)v.w);
    qb4[i] = h;
  }
  for (int off = 32; off > 0; off >>= 1) {
    vmin = min(vmin, __shfl_down(vmin, off));
    vmax = max(vmax, __shfl_down(vmax, off));
  }
  __shared__ int rmin[4], rmax[4];
  const int wave = threadIdx.x >> 6;
  if ((threadIdx.x & 63) == 0) { rmin[wave] = vmin; rmax[wave] = vmax; }
  __syncthreads();
  if (threadIdx.x == 0) {
    pmin[blockIdx.x] = min(min(rmin[0], rmin[1]), min(rmin[2], rmin[3]));
    pmax[blockIdx.x] = max(max(rmax[0], rmax[1]), max(rmax[2], rmax[3]));
  }
}

// ---------------- weight min/max only (fallback path, partials) ----------------
__global__ __launch_bounds__(256) void k_wmm(const int* __restrict__ q,
                                             int* __restrict__ pmin,
                                             int* __restrict__ pmax) {
  const int n4 = (OUT_F * IN_F) / 4;
  const int stride = gridDim.x * blockDim.x;
  int vmin = INT_MAX, vmax = INT_MIN;
  const int4* q4 = (const int4*)q;
  for (int i = blockIdx.x * blockDim.x + threadIdx.x; i < n4; i += stride) {
    int4 v = q4[i];
    vmin = min(vmin, min(min(v.x, v.y), min(v.z, v.w)));
    vmax = max(vmax, max(max(v.x, v.y), max(v.z, v.w)));
  }
  for (int off = 32; off > 0; off >>= 1) {
    vmin = min(vmin, __shfl_down(vmin, off));
    vmax = max(vmax, __shfl_down(vmax, off));
  }
  __shared__ int rmin[4], rmax[4];
  const int wave = threadIdx.x >> 6;
  if ((threadIdx.x & 63) == 0) { rmin[wave] = vmin; rmax[wave] = vmax; }
  __syncthreads();
  if (threadIdx.x == 0) {
    pmin[blockIdx.x] = min(min(rmin[0], rmin[1]), min(rmin[2], rmin[3]));
    pmax[blockIdx.x] = max(max(rmax[0], rmax[1]), max(rmax[2], rmax[3]));
  }
}

// ---------------- convert x fp32 -> bf16, fused row sums ----------------
__global__ __launch_bounds__(256) void k_convx(const float* __restrict__ x,
                                               unsigned short* __restrict__ xb,
                                               float* __restrict__ rowsum) {
  const int row = blockIdx.x;
  const float4* xr = (const float4*)(x + (size_t)row * IN_F);
  ushort4* xbr = (ushort4*)(xb + (size_t)row * IN_F);
  float s = 0.f;
  for (int i = threadIdx.x; i < IN_F / 4; i += blockDim.x) {
    float4 v = xr[i];
    s += (v.x + v.y) + (v.z + v.w);
    ushort4 h;
    h.x = f2bf_rne(v.x); h.y = f2bf_rne(v.y);
    h.z = f2bf_rne(v.z); h.w = f2bf_rne(v.w);
    xbr[i] = h;
  }
  __shared__ float red[4];
  for (int off = 32; off > 0; off >>= 1) s += __shfl_down(s, off);
  if ((threadIdx.x & 63) == 0) red[threadIdx.x >> 6] = s;
  __syncthreads();
  if (threadIdx.x == 0) rowsum[row] = (red[0] + red[1]) + (red[2] + red[3]);
}

// ---------------- reduce partials + bias min/max, compute affine scalars ----------------
__global__ __launch_bounds__(256) void k_scal(const int* __restrict__ pmin,
                                              const int* __restrict__ pmax, int npart,
                                              const int* __restrict__ bq,
                                              const float* __restrict__ wmn,
                                              const float* __restrict__ wmx,
                                              const float* __restrict__ bmn,
                                              const float* __restrict__ bmx,
                                              float* __restrict__ scal) {
  int vmin = INT_MAX, vmax = INT_MIN;
  for (int i = threadIdx.x; i < npart; i += 256) {
    vmin = min(vmin, pmin[i]);
    vmax = max(vmax, pmax[i]);
  }
  int bmin = INT_MAX, bmaxv = INT_MIN;
  for (int i = threadIdx.x; i < OUT_F; i += 256) {
    int v = bq[i];
    bmin = min(bmin, v);
    bmaxv = max(bmaxv, v);
  }
  for (int off = 32; off > 0; off >>= 1) {
    vmin = min(vmin, __shfl_down(vmin, off));
    vmax = max(vmax, __shfl_down(vmax, off));
    bmin = min(bmin, __shfl_down(bmin, off));
    bmaxv = max(bmaxv, __shfl_down(bmaxv, off));
  }
  __shared__ int r[4][4];
  const int wave = threadIdx.x >> 6;
  if ((threadIdx.x & 63) == 0) {
    r[wave][0] = vmin; r[wave][1] = vmax; r[wave][2] = bmin; r[wave][3] = bmaxv;
  }
  __syncthreads();
  if (threadIdx.x == 0) {
    int qmin = min(min(r[0][0], r[1][0]), min(r[2][0], r[3][0]));
    int qmax = max(max(r[0][1], r[1][1]), max(r[2][1], r[3][1]));
    int qbmin = min(min(r[0][2], r[1][2]), min(r[2][2], r[3][2]));
    int qbmax = max(max(r[0][3], r[1][3]), max(r[2][3], r[3][3]));
    float ws = (*wmx - *wmn) / (float)(qmax - qmin);
    scal[0] = ws;
    scal[1] = *wmn - ws * (float)qmin;
    float bs = (*bmx - *bmn) / (float)(qbmax - qbmin);
    scal[2] = bs;
    scal[3] = *bmn - bs * (float)qbmin;
  }
}

// ---------------- async global->LDS, 16B per lane, wave-uniform LDS base ----------------
__device__ __forceinline__ void load_lds16(const unsigned short* g, unsigned short* l) {
  __builtin_amdgcn_global_load_lds(
      (const __attribute__((address_space(1))) unsigned int*)g,
      (__attribute__((address_space(3))) unsigned int*)l, 16, 0, 0);
}

// ---------------- 128x128-tile bf16 MFMA GEMM: C = A @ B^T (both K-contiguous) ----------------
// epilogue: out = wscale*acc + wbeta*rowsum[m] + (bscale*bias_q[n] + bbeta)
__global__ __launch_bounds__(256) void k_gemm(
    const unsigned short* __restrict__ A,   // x   bf16 [BATCH][IN_F]
    const unsigned short* __restrict__ B,   // Q   bf16 [OUT_F][IN_F]
    const int* __restrict__ bq,
    const float* __restrict__ rowsum,
    const float* __restrict__ scal,
    float* __restrict__ C) {
  __shared__ unsigned short As[128 * 32];   // 8 KB, row-major [128][32], NO padding (global_load_lds)
  __shared__ unsigned short Bs[128 * 32];

  const int tid = threadIdx.x;
  const int wave = tid >> 6;
  const int lane = tid & 63;
  const int bm = blockIdx.x * 128;
  const int bn = blockIdx.y * 128;

  const int wm = (wave & 1) * 64;   // wave's 64x64 subtile
  const int wn = (wave >> 1) * 64;
  const int row16 = lane & 15;
  const int quad = lane >> 4;

  // staging: 8 chunks of 1KB per tile (64 lanes x 16B); wave handles chunks 2w, 2w+1
  const int c0 = wave * 2;
  const int r0 = c0 * 16 + (lane >> 2);
  const int r1 = r0 + 16;
  const int ccol = (lane & 3) * 8;
  const unsigned short* Ap0 = A + (size_t)(bm + r0) * IN_F + ccol;
  const unsigned short* Ap1 = A + (size_t)(bm + r1) * IN_F + ccol;
  const unsigned short* Bp0 = B + (size_t)(bn + r0) * IN_F + ccol;
  const unsigned short* Bp1 = B + (size_t)(bn + r1) * IN_F + ccol;
  unsigned short* As0 = &As[c0 * 512];
  unsigned short* As1 = &As[(c0 + 1) * 512];
  unsigned short* Bs0 = &Bs[c0 * 512];
  unsigned short* Bs1 = &Bs[(c0 + 1) * 512];

  f32x4 acc[4][4] = {};

  for (int k0 = 0; k0 < IN_F; k0 += 32) {
    load_lds16(Ap0 + k0, As0);
    load_lds16(Ap1 + k0, As1);
    load_lds16(Bp0 + k0, Bs0);
    load_lds16(Bp1 + k0, Bs1);
    __syncthreads();   // drains vmcnt -> LDS tiles ready

    bf16x8 af[4], bfr[4];
#pragma unroll
    for (int i = 0; i < 4; ++i)
      af[i] = *(const bf16x8*)&As[(wm + i * 16 + row16) * 32 + quad * 8];
#pragma unroll
    for (int i = 0; i < 4; ++i)
      bfr[i] = *(const bf16x8*)&Bs[(wn + i * 16 + row16) * 32 + quad * 8];
#pragma unroll
    for (int mi = 0; mi < 4; ++mi)
#pragma unroll
      for (int ni = 0; ni < 4; ++ni)
        acc[mi][ni] = __builtin_amdgcn_mfma_f32_16x16x32_bf16(af[mi], bfr[ni], acc[mi][ni], 0, 0, 0);

    __syncthreads();   // all reads done before next overwrite
  }

  const float wsc = scal[0], wbe = scal[1], bsc = scal[2], bbe = scal[3];
#pragma unroll
  for (int ni = 0; ni < 4; ++ni) {
    const int gn = bn + wn + ni * 16 + row16;          // C/D: col = lane&15
    const float bdq = bsc * (float)bq[gn] + bbe;
#pragma unroll
    for (int mi = 0; mi < 4; ++mi) {
      const int gm0 = bm + wm + mi * 16 + quad * 4;    // C/D: row = quad*4 + reg
#pragma unroll
      for (int r = 0; r < 4; ++r) {
        const int gm = gm0 + r;
        C[(size_t)gm * OUT_F + gn] = wsc * acc[mi][ni][r] + wbe * rowsum[gm] + bdq;
      }
    }
  }
}

// ---------------- fallback (workspace too small): dequant-on-the-fly naive GEMM ----------------
__global__ void k_naive(const float* __restrict__ x, const int* __restrict__ wq,
                        const int* __restrict__ bq, const float* __restrict__ scal,
                        float* __restrict__ out) {
  const int o = blockIdx.x * blockDim.x + threadIdx.x;
  const int b = blockIdx.y;
  const float* xr = x + (size_t)b * IN_F;
  const int* wr = wq + (size_t)o * IN_F;
  float s = 0.f, sx = 0.f;
  for (int k = 0; k < IN_F; ++k) {
    float xv = xr[k];
    s += xv * (float)wr[k];
    sx += xv;
  }
  out[(size_t)b * OUT_F + o] =
      scal[0] * s + scal[1] * sx + scal[2] * (float)bq[o] + scal[3];
}

extern "C" void kernel_launch(void* const* d_in, const int* in_sizes, int n_in,
                              void* d_out, int out_size, void* d_ws, size_t ws_size,
                              hipStream_t stream) {
  const float* x = (const float*)d_in[0];
  const int* wq = (const int*)d_in[1];
  const int* bq = (const int*)d_in[2];
  const float* wmn = (const float*)d_in[3];
  const float* wmx = (const float*)d_in[4];
  const float* bmn = (const float*)d_in[5];
  const float* bmx = (const float*)d_in[6];
  float* out = (float*)d_out;

  char* ws = (char*)d_ws;
  float* scal = (float*)ws;                                  // 16 B
  int* pmin = (int*)(ws + 64);                               // 4 KB
  int* pmax = (int*)(ws + 64 + NPART * 4);                   // 4 KB
  float* rowsum = (float*)(ws + 64 + 2 * NPART * 4);         // 16 KB
  unsigned short* xb = (unsigned short*)(ws + 32768);
  unsigned short* qb = xb + (size_t)BATCH * IN_F;
  const size_t needed = 32768 + (size_t)BATCH * IN_F * 2 + (size_t)OUT_F * IN_F * 2;

  if (ws_size >= needed) {
    k_convq<<<NPART, 256, 0, stream>>>(wq, qb, pmin, pmax);
    k_convx<<<BATCH, 256, 0, stream>>>(x, xb, rowsum);
    k_scal<<<1, 256, 0, stream>>>(pmin, pmax, NPART, bq, wmn, wmx, bmn, bmx, scal);
    dim3 grid(BATCH / 128, OUT_F / 128);
    k_gemm<<<grid, 256, 0, stream>>>(xb, qb, bq, rowsum, scal, out);
  } else {
    k_wmm<<<NPART, 256, 0, stream>>>(wq, pmin, pmax);
    k_scal<<<1, 256, 0, stream>>>(pmin, pmax, NPART, bq, wmn, wmx, bmn, bmx, scal);
    k_naive<<<dim3(OUT_F / 256, BATCH), 256, 0, stream>>>(x, wq, bq, scal, out);
  }
}

// Round 3
// 357.812 us; speedup vs baseline: 2.0226x; 1.0072x over previous
//
#include <hip/hip_runtime.h>
#include <climits>

#define IN_F 4096
#define OUT_F 4096
#define BATCH 4096
#define NPART 1024   // partial-reduction slots for weight min/max

typedef __bf16 bf16x8 __attribute__((ext_vector_type(8)));
typedef float f32x4 __attribute__((ext_vector_type(4)));

__device__ __forceinline__ unsigned short f2bf_rne(float f) {
  unsigned int u = __float_as_uint(f);
  u += 0x7fffu + ((u >> 16) & 1u);
  return (unsigned short)(u >> 16);
}

// ---------------- fused conversion kernel ----------------
// blocks [0, NPART):        weights int32 -> bf16 (exact), per-block partial min/max
// blocks [NPART, 2*NPART):  x fp32 -> bf16 + per-row sums (1 wave per row, 4 rows/block)
__global__ __launch_bounds__(256) void k_conv(const float* __restrict__ x,
                                              const int* __restrict__ q,
                                              unsigned short* __restrict__ xb,
                                              unsigned short* __restrict__ qb,
                                              float* __restrict__ rowsum,
                                              int* __restrict__ pmin,
                                              int* __restrict__ pmax) {
  if (blockIdx.x < NPART) {
    // ---- weight conversion + min/max partials (no global atomics: R1 showed
    // 16K same-address atomicMin/Max serialize at ~28 cyc each = 383 us) ----
    const int n4 = (OUT_F * IN_F) / 4;
    const int stride = NPART * 256;
    int vmin = INT_MAX, vmax = INT_MIN;
    const int4* q4 = (const int4*)q;
    ushort4* qb4 = (ushort4*)qb;
    for (int i = blockIdx.x * 256 + threadIdx.x; i < n4; i += stride) {
      int4 v = q4[i];
      vmin = min(vmin, min(min(v.x, v.y), min(v.z, v.w)));
      vmax = max(vmax, max(max(v.x, v.y), max(v.z, v.w)));
      ushort4 h;
      h.x = f2bf_rne((float)v.x);  // |q| <= 255 -> exact in bf16
      h.y = f2bf_rne((float)v.y);
      h.z = f2bf_rne((float)v.z);
      h.w = f2bf_rne((float)v.w);
      qb4[i] = h;
    }
    for (int off = 32; off > 0; off >>= 1) {
      vmin = min(vmin, __shfl_down(vmin, off));
      vmax = max(vmax, __shfl_down(vmax, off));
    }
    __shared__ int rmin[4], rmax[4];
    const int wave = threadIdx.x >> 6;
    if ((threadIdx.x & 63) == 0) { rmin[wave] = vmin; rmax[wave] = vmax; }
    __syncthreads();
    if (threadIdx.x == 0) {
      pmin[blockIdx.x] = min(min(rmin[0], rmin[1]), min(rmin[2], rmin[3]));
      pmax[blockIdx.x] = max(max(rmax[0], rmax[1]), max(rmax[2], rmax[3]));
    }
  } else {
    // ---- x conversion + rowsum: wave w handles row 4*b + w ----
    const int wave = threadIdx.x >> 6;
    const int lane = threadIdx.x & 63;
    const int row = (blockIdx.x - NPART) * 4 + wave;
    const float4* xr = (const float4*)(x + (size_t)row * IN_F);
    ushort4* xbr = (ushort4*)(xb + (size_t)row * IN_F);
    float s = 0.f;
#pragma unroll
    for (int it = 0; it < IN_F / 4 / 64; ++it) {
      const int i = it * 64 + lane;
      float4 v = xr[i];
      s += (v.x + v.y) + (v.z + v.w);
      ushort4 h;
      h.x = f2bf_rne(v.x); h.y = f2bf_rne(v.y);
      h.z = f2bf_rne(v.z); h.w = f2bf_rne(v.w);
      xbr[i] = h;
    }
    for (int off = 32; off > 0; off >>= 1) s += __shfl_down(s, off);
    if (lane == 0) rowsum[row] = s;
  }
}

// ---------------- weight min/max only (fallback path, partials) ----------------
__global__ __launch_bounds__(256) void k_wmm(const int* __restrict__ q,
                                             int* __restrict__ pmin,
                                             int* __restrict__ pmax) {
  const int n4 = (OUT_F * IN_F) / 4;
  const int stride = gridDim.x * blockDim.x;
  int vmin = INT_MAX, vmax = INT_MIN;
  const int4* q4 = (const int4*)q;
  for (int i = blockIdx.x * blockDim.x + threadIdx.x; i < n4; i += stride) {
    int4 v = q4[i];
    vmin = min(vmin, min(min(v.x, v.y), min(v.z, v.w)));
    vmax = max(vmax, max(max(v.x, v.y), max(v.z, v.w)));
  }
  for (int off = 32; off > 0; off >>= 1) {
    vmin = min(vmin, __shfl_down(vmin, off));
    vmax = max(vmax, __shfl_down(vmax, off));
  }
  __shared__ int rmin[4], rmax[4];
  const int wave = threadIdx.x >> 6;
  if ((threadIdx.x & 63) == 0) { rmin[wave] = vmin; rmax[wave] = vmax; }
  __syncthreads();
  if (threadIdx.x == 0) {
    pmin[blockIdx.x] = min(min(rmin[0], rmin[1]), min(rmin[2], rmin[3]));
    pmax[blockIdx.x] = max(max(rmax[0], rmax[1]), max(rmax[2], rmax[3]));
  }
}

// ---------------- reduce partials + bias min/max, compute affine scalars ----------------
__global__ __launch_bounds__(256) void k_scal(const int* __restrict__ pmin,
                                              const int* __restrict__ pmax, int npart,
                                              const int* __restrict__ bq,
                                              const float* __restrict__ wmn,
                                              const float* __restrict__ wmx,
                                              const float* __restrict__ bmn,
                                              const float* __restrict__ bmx,
                                              float* __restrict__ scal) {
  int vmin = INT_MAX, vmax = INT_MIN;
  for (int i = threadIdx.x; i < npart; i += 256) {
    vmin = min(vmin, pmin[i]);
    vmax = max(vmax, pmax[i]);
  }
  int bmin = INT_MAX, bmaxv = INT_MIN;
  for (int i = threadIdx.x; i < OUT_F; i += 256) {
    int v = bq[i];
    bmin = min(bmin, v);
    bmaxv = max(bmaxv, v);
  }
  for (int off = 32; off > 0; off >>= 1) {
    vmin = min(vmin, __shfl_down(vmin, off));
    vmax = max(vmax, __shfl_down(vmax, off));
    bmin = min(bmin, __shfl_down(bmin, off));
    bmaxv = max(bmaxv, __shfl_down(bmaxv, off));
  }
  __shared__ int r[4][4];
  const int wave = threadIdx.x >> 6;
  if ((threadIdx.x & 63) == 0) {
    r[wave][0] = vmin; r[wave][1] = vmax; r[wave][2] = bmin; r[wave][3] = bmaxv;
  }
  __syncthreads();
  if (threadIdx.x == 0) {
    int qmin = min(min(r[0][0], r[1][0]), min(r[2][0], r[3][0]));
    int qmax = max(max(r[0][1], r[1][1]), max(r[2][1], r[3][1]));
    int qbmin = min(min(r[0][2], r[1][2]), min(r[2][2], r[3][2]));
    int qbmax = max(max(r[0][3], r[1][3]), max(r[2][3], r[3][3]));
    float ws = (*wmx - *wmn) / (float)(qmax - qmin);
    scal[0] = ws;
    scal[1] = *wmn - ws * (float)qmin;
    float bs = (*bmx - *bmn) / (float)(qbmax - qbmin);
    scal[2] = bs;
    scal[3] = *bmn - bs * (float)qbmin;
  }
}

// ---------------- async global->LDS, 16B per lane, wave-uniform LDS base ----------------
__device__ __forceinline__ void load_lds16(const unsigned short* g, unsigned short* l) {
  __builtin_amdgcn_global_load_lds(
      (const __attribute__((address_space(1))) unsigned int*)g,
      (__attribute__((address_space(3))) unsigned int*)l, 16, 0, 0);
}

// ---------------- 128x128-tile bf16 MFMA GEMM: C = A @ B^T (both K-contiguous) ----------------
// LDS tile layout is XOR-swizzled: row r's 16B chunk c lives at chunk c ^ ((r>>1)&3).
// R2 profile: un-swizzled row-major gave 8-way bank conflicts on every ds_read_b128
// (SQ_LDS_BANK_CONFLICT=1.68e7 = ~27us/CU tax). Swizzle spreads the 16 rows of a
// quarter-wave read over 8 bank-groups x 2-way (2-way is free, m136).
// Swizzle is applied on the STAGING side by permuting each lane's global source
// chunk (global_load_lds pins LDS slot = base + 16*lane): lane i loads chunk
// (i&3)^((i>>3)&3) of its row -- a permutation within one 64B segment, coalesced.
__global__ __launch_bounds__(256) void k_gemm(
    const unsigned short* __restrict__ A,   // x   bf16 [BATCH][IN_F]
    const unsigned short* __restrict__ B,   // Q   bf16 [OUT_F][IN_F]
    const int* __restrict__ bq,
    const float* __restrict__ rowsum,
    const float* __restrict__ scal,
    float* __restrict__ C) {
  __shared__ unsigned short As[128 * 32];   // 8 KB, swizzled [128][4 chunks of 16B]
  __shared__ unsigned short Bs[128 * 32];

  const int tid = threadIdx.x;
  const int wave = tid >> 6;
  const int lane = tid & 63;
  const int bm = blockIdx.x * 128;
  const int bn = blockIdx.y * 128;

  const int wm = (wave & 1) * 64;   // wave's 64x64 subtile
  const int wn = (wave >> 1) * 64;
  const int row16 = lane & 15;
  const int quad = lane >> 4;

  // staging: 8 chunks of 1KB per tile (64 lanes x 16B); wave handles chunks 2w, 2w+1
  const int c0 = wave * 2;
  const int r0 = c0 * 16 + (lane >> 2);
  const int r1 = r0 + 16;
  const int ccol = ((lane & 3) ^ ((lane >> 3) & 3)) * 8;   // XOR-swizzled source chunk
  const unsigned short* Ap0 = A + (size_t)(bm + r0) * IN_F + ccol;
  const unsigned short* Ap1 = A + (size_t)(bm + r1) * IN_F + ccol;
  const unsigned short* Bp0 = B + (size_t)(bn + r0) * IN_F + ccol;
  const unsigned short* Bp1 = B + (size_t)(bn + r1) * IN_F + ccol;
  unsigned short* As0 = &As[c0 * 512];
  unsigned short* As1 = &As[(c0 + 1) * 512];
  unsigned short* Bs0 = &Bs[c0 * 512];
  unsigned short* Bs1 = &Bs[(c0 + 1) * 512];

  // swizzled read chunk: c_lds = quad ^ ((r>>1)&3); (r>>1)&3 == (lane>>1)&3 here
  const int cread = (quad ^ ((lane >> 1) & 3)) * 8;

  f32x4 acc[4][4] = {};

  for (int k0 = 0; k0 < IN_F; k0 += 32) {
    load_lds16(Ap0 + k0, As0);
    load_lds16(Ap1 + k0, As1);
    load_lds16(Bp0 + k0, Bs0);
    load_lds16(Bp1 + k0, Bs1);
    __syncthreads();   // drains vmcnt -> LDS tiles ready

    bf16x8 af[4], bfr[4];
#pragma unroll
    for (int i = 0; i < 4; ++i)
      af[i] = *(const bf16x8*)&As[(wm + i * 16 + row16) * 32 + cread];
#pragma unroll
    for (int i = 0; i < 4; ++i)
      bfr[i] = *(const bf16x8*)&Bs[(wn + i * 16 + row16) * 32 + cread];
#pragma unroll
    for (int mi = 0; mi < 4; ++mi)
#pragma unroll
      for (int ni = 0; ni < 4; ++ni)
        acc[mi][ni] = __builtin_amdgcn_mfma_f32_16x16x32_bf16(af[mi], bfr[ni], acc[mi][ni], 0, 0, 0);

    __syncthreads();   // all reads done before next overwrite
  }

  const float wsc = scal[0], wbe = scal[1], bsc = scal[2], bbe = scal[3];
#pragma unroll
  for (int ni = 0; ni < 4; ++ni) {
    const int gn = bn + wn + ni * 16 + row16;          // C/D: col = lane&15
    const float bdq = bsc * (float)bq[gn] + bbe;
#pragma unroll
    for (int mi = 0; mi < 4; ++mi) {
      const int gm0 = bm + wm + mi * 16 + quad * 4;    // C/D: row = quad*4 + reg
#pragma unroll
      for (int r = 0; r < 4; ++r) {
        const int gm = gm0 + r;
        C[(size_t)gm * OUT_F + gn] = wsc * acc[mi][ni][r] + wbe * rowsum[gm] + bdq;
      }
    }
  }
}

// ---------------- fallback (workspace too small): dequant-on-the-fly naive GEMM ----------------
__global__ void k_naive(const float* __restrict__ x, const int* __restrict__ wq,
                        const int* __restrict__ bq, const float* __restrict__ scal,
                        float* __restrict__ out) {
  const int o = blockIdx.x * blockDim.x + threadIdx.x;
  const int b = blockIdx.y;
  const float* xr = x + (size_t)b * IN_F;
  const int* wr = wq + (size_t)o * IN_F;
  float s = 0.f, sx = 0.f;
  for (int k = 0; k < IN_F; ++k) {
    float xv = xr[k];
    s += xv * (float)wr[k];
    sx += xv;
  }
  out[(size_t)b * OUT_F + o] =
      scal[0] * s + scal[1] * sx + scal[2] * (float)bq[o] + scal[3];
}

extern "C" void kernel_launch(void* const* d_in, const int* in_sizes, int n_in,
                              void* d_out, int out_size, void* d_ws, size_t ws_size,
                              hipStream_t stream) {
  const float* x = (const float*)d_in[0];
  const int* wq = (const int*)d_in[1];
  const int* bq = (const int*)d_in[2];
  const float* wmn = (const float*)d_in[3];
  const float* wmx = (const float*)d_in[4];
  const float* bmn = (const float*)d_in[5];
  const float* bmx = (const float*)d_in[6];
  float* out = (float*)d_out;

  char* ws = (char*)d_ws;
  float* scal = (float*)ws;                                  // 16 B
  int* pmin = (int*)(ws + 64);                               // 4 KB
  int* pmax = (int*)(ws + 64 + NPART * 4);                   // 4 KB
  float* rowsum = (float*)(ws + 64 + 2 * NPART * 4);         // 16 KB
  unsigned short* xb = (unsigned short*)(ws + 32768);
  unsigned short* qb = xb + (size_t)BATCH * IN_F;
  const size_t needed = 32768 + (size_t)BATCH * IN_F * 2 + (size_t)OUT_F * IN_F * 2;

  if (ws_size >= needed) {
    k_conv<<<2 * NPART, 256, 0, stream>>>(x, wq, xb, qb, rowsum, pmin, pmax);
    k_scal<<<1, 256, 0, stream>>>(pmin, pmax, NPART, bq, wmn, wmx, bmn, bmx, scal);
    dim3 grid(BATCH / 128, OUT_F / 128);
    k_gemm<<<grid, 256, 0, stream>>>(xb, qb, bq, rowsum, scal, out);
  } else {
    k_wmm<<<NPART, 256, 0, stream>>>(wq, pmin, pmax);
    k_scal<<<1, 256, 0, stream>>>(pmin, pmax, NPART, bq, wmn, wmx, bmn, bmx, scal);
    k_naive<<<dim3(OUT_F / 256, BATCH), 256, 0, stream>>>(x, wq, bq, scal, out);
  }
}

// Round 4
// 344.737 us; speedup vs baseline: 2.0993x; 1.0379x over previous
//
#include <hip/hip_runtime.h>
#include <climits>

#define IN_F 4096
#define OUT_F 4096
#define BATCH 4096
#define NPART 1024   // partial-reduction slots for weight min/max

typedef __bf16 bf16x8 __attribute__((ext_vector_type(8)));
typedef float f32x4 __attribute__((ext_vector_type(4)));

__device__ __forceinline__ unsigned short f2bf_rne(float f) {
  unsigned int u = __float_as_uint(f);
  u += 0x7fffu + ((u >> 16) & 1u);
  return (unsigned short)(u >> 16);
}

// ---------------- fused conversion kernel ----------------
// blocks [0, NPART):        weights int32 -> bf16 (exact), per-block partial min/max
// blocks [NPART, 2*NPART):  x fp32 -> bf16 + per-row sums (1 wave per row, 4 rows/block)
__global__ __launch_bounds__(256) void k_conv(const float* __restrict__ x,
                                              const int* __restrict__ q,
                                              unsigned short* __restrict__ xb,
                                              unsigned short* __restrict__ qb,
                                              float* __restrict__ rowsum,
                                              int* __restrict__ pmin,
                                              int* __restrict__ pmax) {
  if (blockIdx.x < NPART) {
    // ---- weight conversion + min/max partials (no global atomics: R1 showed
    // 16K same-address atomicMin/Max serialize at ~28 cyc each = 383 us) ----
    const int n4 = (OUT_F * IN_F) / 4;
    const int stride = NPART * 256;
    int vmin = INT_MAX, vmax = INT_MIN;
    const int4* q4 = (const int4*)q;
    ushort4* qb4 = (ushort4*)qb;
    for (int i = blockIdx.x * 256 + threadIdx.x; i < n4; i += stride) {
      int4 v = q4[i];
      vmin = min(vmin, min(min(v.x, v.y), min(v.z, v.w)));
      vmax = max(vmax, max(max(v.x, v.y), max(v.z, v.w)));
      ushort4 h;
      h.x = f2bf_rne((float)v.x);  // |q| <= 255 -> exact in bf16
      h.y = f2bf_rne((float)v.y);
      h.z = f2bf_rne((float)v.z);
      h.w = f2bf_rne((float)v.w);
      qb4[i] = h;
    }
    for (int off = 32; off > 0; off >>= 1) {
      vmin = min(vmin, __shfl_down(vmin, off));
      vmax = max(vmax, __shfl_down(vmax, off));
    }
    __shared__ int rmin[4], rmax[4];
    const int wave = threadIdx.x >> 6;
    if ((threadIdx.x & 63) == 0) { rmin[wave] = vmin; rmax[wave] = vmax; }
    __syncthreads();
    if (threadIdx.x == 0) {
      pmin[blockIdx.x] = min(min(rmin[0], rmin[1]), min(rmin[2], rmin[3]));
      pmax[blockIdx.x] = max(max(rmax[0], rmax[1]), max(rmax[2], rmax[3]));
    }
  } else {
    // ---- x conversion + rowsum: wave w handles row 4*b + w ----
    const int wave = threadIdx.x >> 6;
    const int lane = threadIdx.x & 63;
    const int row = (blockIdx.x - NPART) * 4 + wave;
    const float4* xr = (const float4*)(x + (size_t)row * IN_F);
    ushort4* xbr = (ushort4*)(xb + (size_t)row * IN_F);
    float s = 0.f;
#pragma unroll
    for (int it = 0; it < IN_F / 4 / 64; ++it) {
      const int i = it * 64 + lane;
      float4 v = xr[i];
      s += (v.x + v.y) + (v.z + v.w);
      ushort4 h;
      h.x = f2bf_rne(v.x); h.y = f2bf_rne(v.y);
      h.z = f2bf_rne(v.z); h.w = f2bf_rne(v.w);
      xbr[i] = h;
    }
    for (int off = 32; off > 0; off >>= 1) s += __shfl_down(s, off);
    if (lane == 0) rowsum[row] = s;
  }
}

// ---------------- weight min/max only (fallback path, partials) ----------------
__global__ __launch_bounds__(256) void k_wmm(const int* __restrict__ q,
                                             int* __restrict__ pmin,
                                             int* __restrict__ pmax) {
  const int n4 = (OUT_F * IN_F) / 4;
  const int stride = gridDim.x * blockDim.x;
  int vmin = INT_MAX, vmax = INT_MIN;
  const int4* q4 = (const int4*)q;
  for (int i = blockIdx.x * blockDim.x + threadIdx.x; i < n4; i += stride) {
    int4 v = q4[i];
    vmin = min(vmin, min(min(v.x, v.y), min(v.z, v.w)));
    vmax = max(vmax, max(max(v.x, v.y), max(v.z, v.w)));
  }
  for (int off = 32; off > 0; off >>= 1) {
    vmin = min(vmin, __shfl_down(vmin, off));
    vmax = max(vmax, __shfl_down(vmax, off));
  }
  __shared__ int rmin[4], rmax[4];
  const int wave = threadIdx.x >> 6;
  if ((threadIdx.x & 63) == 0) { rmin[wave] = vmin; rmax[wave] = vmax; }
  __syncthreads();
  if (threadIdx.x == 0) {
    pmin[blockIdx.x] = min(min(rmin[0], rmin[1]), min(rmin[2], rmin[3]));
    pmax[blockIdx.x] = max(max(rmax[0], rmax[1]), max(rmax[2], rmax[3]));
  }
}

// ---------------- reduce partials + bias min/max, compute affine scalars ----------------
__global__ __launch_bounds__(256) void k_scal(const int* __restrict__ pmin,
                                              const int* __restrict__ pmax, int npart,
                                              const int* __restrict__ bq,
                                              const float* __restrict__ wmn,
                                              const float* __restrict__ wmx,
                                              const float* __restrict__ bmn,
                                              const float* __restrict__ bmx,
                                              float* __restrict__ scal) {
  int vmin = INT_MAX, vmax = INT_MIN;
  for (int i = threadIdx.x; i < npart; i += 256) {
    vmin = min(vmin, pmin[i]);
    vmax = max(vmax, pmax[i]);
  }
  int bmin = INT_MAX, bmaxv = INT_MIN;
  for (int i = threadIdx.x; i < OUT_F; i += 256) {
    int v = bq[i];
    bmin = min(bmin, v);
    bmaxv = max(bmaxv, v);
  }
  for (int off = 32; off > 0; off >>= 1) {
    vmin = min(vmin, __shfl_down(vmin, off));
    vmax = max(vmax, __shfl_down(vmax, off));
    bmin = min(bmin, __shfl_down(bmin, off));
    bmaxv = max(bmaxv, __shfl_down(bmaxv, off));
  }
  __shared__ int r[4][4];
  const int wave = threadIdx.x >> 6;
  if ((threadIdx.x & 63) == 0) {
    r[wave][0] = vmin; r[wave][1] = vmax; r[wave][2] = bmin; r[wave][3] = bmaxv;
  }
  __syncthreads();
  if (threadIdx.x == 0) {
    int qmin = min(min(r[0][0], r[1][0]), min(r[2][0], r[3][0]));
    int qmax = max(max(r[0][1], r[1][1]), max(r[2][1], r[3][1]));
    int qbmin = min(min(r[0][2], r[1][2]), min(r[2][2], r[3][2]));
    int qbmax = max(max(r[0][3], r[1][3]), max(r[2][3], r[3][3]));
    float ws = (*wmx - *wmn) / (float)(qmax - qmin);
    scal[0] = ws;
    scal[1] = *wmn - ws * (float)qmin;
    float bs = (*bmx - *bmn) / (float)(qbmax - qbmin);
    scal[2] = bs;
    scal[3] = *bmn - bs * (float)qbmin;
  }
}

// ---------------- async global->LDS, 16B per lane, wave-uniform LDS base ----------------
__device__ __forceinline__ void load_lds16(const unsigned short* g, unsigned short* l) {
  __builtin_amdgcn_global_load_lds(
      (const __attribute__((address_space(1))) unsigned int*)g,
      (__attribute__((address_space(3))) unsigned int*)l, 16, 0, 0);
}

// ---------------- 128x128-tile bf16 MFMA GEMM: C = A @ B^T (both K-contiguous) ----------------
// LDS tile layout is XOR-swizzled: row r's 16B chunk c lives at chunk c ^ ((r>>1)&3)
// (R2->R3: SQ_LDS_BANK_CONFLICT 1.68e7 -> 0; time-neutral -> conflicts were hidden).
// __launch_bounds__(256, 3): R3 ran at 22% occupancy (2 waves/SIMD) because
// 108 VGPR + 64 AGPR = 172 unified regs/wave > 512/3 = 170 -- two registers over
// the 3-waves/SIMD cliff. Forcing 3 waves/EU shaves ~4 VGPRs, +50% resident waves
// to hide the barrier vmcnt(0) drain (the m97-structure's known ~20% stall).
__global__ __launch_bounds__(256, 3) void k_gemm(
    const unsigned short* __restrict__ A,   // x   bf16 [BATCH][IN_F]
    const unsigned short* __restrict__ B,   // Q   bf16 [OUT_F][IN_F]
    const int* __restrict__ bq,
    const float* __restrict__ rowsum,
    const float* __restrict__ scal,
    float* __restrict__ C) {
  __shared__ unsigned short As[128 * 32];   // 8 KB, swizzled [128][4 chunks of 16B]
  __shared__ unsigned short Bs[128 * 32];

  const int tid = threadIdx.x;
  const int wave = tid >> 6;
  const int lane = tid & 63;
  const int bm = blockIdx.x * 128;
  const int bn = blockIdx.y * 128;

  const int wm = (wave & 1) * 64;   // wave's 64x64 subtile
  const int wn = (wave >> 1) * 64;
  const int row16 = lane & 15;
  const int quad = lane >> 4;

  // staging: 8 chunks of 1KB per tile (64 lanes x 16B); wave handles chunks 2w, 2w+1
  const int c0 = wave * 2;
  const int r0 = c0 * 16 + (lane >> 2);
  const int r1 = r0 + 16;
  const int ccol = ((lane & 3) ^ ((lane >> 3) & 3)) * 8;   // XOR-swizzled source chunk
  const unsigned short* Ap0 = A + (size_t)(bm + r0) * IN_F + ccol;
  const unsigned short* Ap1 = A + (size_t)(bm + r1) * IN_F + ccol;
  const unsigned short* Bp0 = B + (size_t)(bn + r0) * IN_F + ccol;
  const unsigned short* Bp1 = B + (size_t)(bn + r1) * IN_F + ccol;
  unsigned short* As0 = &As[c0 * 512];
  unsigned short* As1 = &As[(c0 + 1) * 512];
  unsigned short* Bs0 = &Bs[c0 * 512];
  unsigned short* Bs1 = &Bs[(c0 + 1) * 512];

  // swizzled read chunk: c_lds = quad ^ ((r>>1)&3); (r>>1)&3 == (lane>>1)&3 here
  const int cread = (quad ^ ((lane >> 1) & 3)) * 8;

  f32x4 acc[4][4] = {};

  for (int k0 = 0; k0 < IN_F; k0 += 32) {
    load_lds16(Ap0 + k0, As0);
    load_lds16(Ap1 + k0, As1);
    load_lds16(Bp0 + k0, Bs0);
    load_lds16(Bp1 + k0, Bs1);
    __syncthreads();   // drains vmcnt -> LDS tiles ready

    bf16x8 af[4], bfr[4];
#pragma unroll
    for (int i = 0; i < 4; ++i)
      af[i] = *(const bf16x8*)&As[(wm + i * 16 + row16) * 32 + cread];
#pragma unroll
    for (int i = 0; i < 4; ++i)
      bfr[i] = *(const bf16x8*)&Bs[(wn + i * 16 + row16) * 32 + cread];
#pragma unroll
    for (int mi = 0; mi < 4; ++mi)
#pragma unroll
      for (int ni = 0; ni < 4; ++ni)
        acc[mi][ni] = __builtin_amdgcn_mfma_f32_16x16x32_bf16(af[mi], bfr[ni], acc[mi][ni], 0, 0, 0);

    __syncthreads();   // all reads done before next overwrite
  }

  const float wsc = scal[0], wbe = scal[1], bsc = scal[2], bbe = scal[3];
#pragma unroll
  for (int ni = 0; ni < 4; ++ni) {
    const int gn = bn + wn + ni * 16 + row16;          // C/D: col = lane&15
    const float bdq = bsc * (float)bq[gn] + bbe;
#pragma unroll
    for (int mi = 0; mi < 4; ++mi) {
      const int gm0 = bm + wm + mi * 16 + quad * 4;    // C/D: row = quad*4 + reg
#pragma unroll
      for (int r = 0; r < 4; ++r) {
        const int gm = gm0 + r;
        C[(size_t)gm * OUT_F + gn] = wsc * acc[mi][ni][r] + wbe * rowsum[gm] + bdq;
      }
    }
  }
}

// ---------------- fallback (workspace too small): dequant-on-the-fly naive GEMM ----------------
__global__ void k_naive(const float* __restrict__ x, const int* __restrict__ wq,
                        const int* __restrict__ bq, const float* __restrict__ scal,
                        float* __restrict__ out) {
  const int o = blockIdx.x * blockDim.x + threadIdx.x;
  const int b = blockIdx.y;
  const float* xr = x + (size_t)b * IN_F;
  const int* wr = wq + (size_t)o * IN_F;
  float s = 0.f, sx = 0.f;
  for (int k = 0; k < IN_F; ++k) {
    float xv = xr[k];
    s += xv * (float)wr[k];
    sx += xv;
  }
  out[(size_t)b * OUT_F + o] =
      scal[0] * s + scal[1] * sx + scal[2] * (float)bq[o] + scal[3];
}

extern "C" void kernel_launch(void* const* d_in, const int* in_sizes, int n_in,
                              void* d_out, int out_size, void* d_ws, size_t ws_size,
                              hipStream_t stream) {
  const float* x = (const float*)d_in[0];
  const int* wq = (const int*)d_in[1];
  const int* bq = (const int*)d_in[2];
  const float* wmn = (const float*)d_in[3];
  const float* wmx = (const float*)d_in[4];
  const float* bmn = (const float*)d_in[5];
  const float* bmx = (const float*)d_in[6];
  float* out = (float*)d_out;

  char* ws = (char*)d_ws;
  float* scal = (float*)ws;                                  // 16 B
  int* pmin = (int*)(ws + 64);                               // 4 KB
  int* pmax = (int*)(ws + 64 + NPART * 4);                   // 4 KB
  float* rowsum = (float*)(ws + 64 + 2 * NPART * 4);         // 16 KB
  unsigned short* xb = (unsigned short*)(ws + 32768);
  unsigned short* qb = xb + (size_t)BATCH * IN_F;
  const size_t needed = 32768 + (size_t)BATCH * IN_F * 2 + (size_t)OUT_F * IN_F * 2;

  if (ws_size >= needed) {
    k_conv<<<2 * NPART, 256, 0, stream>>>(x, wq, xb, qb, rowsum, pmin, pmax);
    k_scal<<<1, 256, 0, stream>>>(pmin, pmax, NPART, bq, wmn, wmx, bmn, bmx, scal);
    dim3 grid(BATCH / 128, OUT_F / 128);
    k_gemm<<<grid, 256, 0, stream>>>(xb, qb, bq, rowsum, scal, out);
  } else {
    k_wmm<<<NPART, 256, 0, stream>>>(wq, pmin, pmax);
    k_scal<<<1, 256, 0, stream>>>(pmin, pmax, NPART, bq, wmn, wmx, bmn, bmx, scal);
    k_naive<<<dim3(OUT_F / 256, BATCH), 256, 0, stream>>>(x, wq, bq, scal, out);
  }
}